// Round 1
// 2009.503 us; speedup vs baseline: 4.4963x; 4.4963x over previous
//
#include <hip/hip_runtime.h>
#include <hip/hip_bf16.h>

typedef unsigned short u16;
typedef unsigned int u32;

#define NB 2
#define NN 384
#define ND 128
#define NE 64
#define NHD 8
#define NHID 256
#define EH1 384
#define EH2 128
#define LN_EPS 1e-5f
#define ATT_SCALE 0.17677669529663687f  // 1/sqrt(NODE_HIDDEN//HEADS)=1/sqrt(32)

#define XOUT_ELEMS (NB * NN * ND)                 // 98304
#define ADJ_ELEMS ((size_t)NB * NN * NN * NE)     // 18874368
#define OUT_ELEMS (XOUT_ELEMS + ADJ_ELEMS)        // 18972672 f32 elements
// f32 scratch carved from the TAIL of the adj-output region (dead until
// k_edge1 writes it, by which time scratch is fully consumed).
#define SCRATCH_F32 (4 * XOUT_ELEMS)              // nq,nk,nv,att

__device__ __forceinline__ float bflo(u32 u) {
  return __builtin_bit_cast(float, u << 16);
}
__device__ __forceinline__ float bfhi(u32 u) {
  return __builtin_bit_cast(float, u & 0xffff0000u);
}
__device__ __forceinline__ u16 bfr(float f) {
  return __builtin_bit_cast(u16, __float2bfloat16(f));
}
__device__ __forceinline__ u32 packbf(float a, float b) {
  return (u32)bfr(a) | ((u32)bfr(b) << 16);
}
__device__ __forceinline__ float wsum64(float v) {
#pragma unroll
  for (int o = 32; o > 0; o >>= 1) v += __shfl_xor(v, o, 64);
  return v;
}
__device__ __forceinline__ float wmax64(float v) {
#pragma unroll
  for (int o = 32; o > 0; o >>= 1) v = fmaxf(v, __shfl_xor(v, o, 64));
  return v;
}

// ---------------- K1: nq/nk/nv = x @ w{q,k,v}.T (f32, plain) ----------------
__global__ void k_node_qkv(const float* __restrict__ x,
                           const float* __restrict__ wq,
                           const float* __restrict__ wk,
                           const float* __restrict__ wv,
                           float* __restrict__ nq, float* __restrict__ nk,
                           float* __restrict__ nv) {
  int row = blockIdx.x;  // b*N+i
  int t = threadIdx.x;   // 128
  __shared__ float xs[ND];
  xs[t] = x[row * ND + t];
  __syncthreads();
  float aq = 0.f, ak = 0.f, av = 0.f;
  for (int k = 0; k < ND; ++k) {
    float xv = xs[k];
    aq += xv * wq[t * ND + k];
    ak += xv * wk[t * ND + k];
    av += xv * wv[t * ND + k];
  }
  nq[row * ND + t] = aq;
  nk[row * ND + t] = ak;
  nv[row * ND + t] = av;
}

// ---------------- K2: attention, LDS-tiled, wave-per-head ----------------
// Per block (b,i):
//  pass1: scores[h][j] = (nq_h + Qe_h a_ij) . (nk_j,h + Ke_h a_ij) * SCALE
//         thread (h = t>>6, lane l) handles j = tile+l and tile+l+64.
//         eq/ek accumulators in registers; adj tile in LDS transposed
//         (stride 129 -> conflict-free b32 reads); bf16 weight pairs read
//         as broadcast ds_read_b128.
//  softmax: wave h reduces its own row via shuffles.
//  pass2: psum[h][k] = sum_j p_hj a_ij[k]  (512 threads = 8h x 64k)
//  epilogue (linearity): out = sum_j p nv_j + Ve * psum  (Ve in f32)
#define TJ 128
struct AttnS {
  u32 wq_p[NE][64];      // 16KB  [k][c2] packs channels (2c2, 2c2+1)
  u32 wk_p[NE][64];      // 16KB
  float a_t[NE][TJ + 1]; // 33024B transposed adj tile: a_t[k][jloc]
  float sc[NHD][NN];     // 12KB  scores -> probs
  float psum[NHD][NE];   // 2KB
};

__global__ void __launch_bounds__(512) k_attn(
    const float* __restrict__ adj,
    const float* __restrict__ weq,
    const float* __restrict__ wek,
    const float* __restrict__ wev,
    const float* __restrict__ nq,
    const float* __restrict__ nk,
    const float* __restrict__ nv,
    float* __restrict__ att) {
  __shared__ AttnS s;
  int bi = blockIdx.x;     // b*N + i
  int b = bi / NN;
  int t = threadIdx.x;     // 512
  int h = t >> 6;          // wave = head
  int l = t & 63;
  int h8 = h * 8;

  // stage bf16 channel-pair weight packs (one-time, L2-hot)
  for (int p = t; p < NE * 64; p += 512) {
    int c2 = p >> 6, k = p & 63;
    s.wq_p[k][c2] = packbf(weq[(2 * c2) * NE + k], weq[(2 * c2 + 1) * NE + k]);
    s.wk_p[k][c2] = packbf(wek[(2 * c2) * NE + k], wek[(2 * c2 + 1) * NE + k]);
  }

  // nq slice for this row/head -> regs (seeds eq accumulators)
  float nqv[16];
  {
    const float* nqr = nq + (size_t)bi * ND + h * 16;
#pragma unroll
    for (int d = 0; d < 16; ++d) nqv[d] = nqr[d];
  }
  __syncthreads();

  // ---------------- pass 1: scores ----------------
  for (int tile = 0; tile < NN / TJ; ++tile) {
    int jbase = tile * TJ;
    __syncthreads();  // protect a_t from previous phase
    {
      const float4* src = (const float4*)(adj + ((size_t)bi * NN + jbase) * NE);
#pragma unroll
      for (int sIdx = 0; sIdx < 4; ++sIdx) {
        int f = t + sIdx * 512;          // float4 index within 128x64 tile
        float4 v = src[f];
        int jl = f >> 4, k4 = (f & 15) * 4;
        s.a_t[k4 + 0][jl] = v.x;
        s.a_t[k4 + 1][jl] = v.y;
        s.a_t[k4 + 2][jl] = v.z;
        s.a_t[k4 + 3][jl] = v.w;
      }
    }
    __syncthreads();

    float eq0[16], ek0[16], eq1[16], ek1[16];
#pragma unroll
    for (int d = 0; d < 16; ++d) {
      eq0[d] = nqv[d]; eq1[d] = nqv[d];
      ek0[d] = 0.f;    ek1[d] = 0.f;
    }
#pragma unroll 2
    for (int k = 0; k < NE; ++k) {
      float a0 = s.a_t[k][l];
      float a1 = s.a_t[k][l + 64];
      uint4 wqa = *(const uint4*)&s.wq_p[k][h8];
      uint4 wqb = *(const uint4*)&s.wq_p[k][h8 + 4];
      uint4 wka = *(const uint4*)&s.wk_p[k][h8];
      uint4 wkb = *(const uint4*)&s.wk_p[k][h8 + 4];
      u32 wq8[8] = {wqa.x, wqa.y, wqa.z, wqa.w, wqb.x, wqb.y, wqb.z, wqb.w};
      u32 wk8[8] = {wka.x, wka.y, wka.z, wka.w, wkb.x, wkb.y, wkb.z, wkb.w};
#pragma unroll
      for (int d2 = 0; d2 < 8; ++d2) {
        float ql = bflo(wq8[d2]), qh = bfhi(wq8[d2]);
        float kl = bflo(wk8[d2]), kh = bfhi(wk8[d2]);
        eq0[2 * d2]     += a0 * ql;
        eq0[2 * d2 + 1] += a0 * qh;
        eq1[2 * d2]     += a1 * ql;
        eq1[2 * d2 + 1] += a1 * qh;
        ek0[2 * d2]     += a0 * kl;
        ek0[2 * d2 + 1] += a0 * kh;
        ek1[2 * d2]     += a1 * kl;
        ek1[2 * d2 + 1] += a1 * kh;
      }
    }
    int j0 = jbase + l, j1 = j0 + 64;
    const float* nkr0 = nk + ((size_t)b * NN + j0) * ND + h * 16;
    const float* nkr1 = nk + ((size_t)b * NN + j1) * ND + h * 16;
    float s0 = 0.f, s1 = 0.f;
#pragma unroll
    for (int d = 0; d < 16; ++d) {
      s0 += eq0[d] * (nkr0[d] + ek0[d]);
      s1 += eq1[d] * (nkr1[d] + ek1[d]);
    }
    s.sc[h][j0] = s0 * ATT_SCALE;
    s.sc[h][j1] = s1 * ATT_SCALE;
  }
  __syncthreads();

  // ---------------- softmax: wave h owns row h ----------------
  {
    float vals[NN / 64];
    float m = -1e30f;
#pragma unroll
    for (int r = 0; r < NN / 64; ++r) {
      vals[r] = s.sc[h][l + 64 * r];
      m = fmaxf(m, vals[r]);
    }
    m = wmax64(m);
    float sum = 0.f;
#pragma unroll
    for (int r = 0; r < NN / 64; ++r) {
      vals[r] = __expf(vals[r] - m);
      sum += vals[r];
    }
    sum = wsum64(sum);
    float rinv = 1.f / sum;
#pragma unroll
    for (int r = 0; r < NN / 64; ++r) s.sc[h][l + 64 * r] = vals[r] * rinv;
  }
  __syncthreads();

  // ---------------- pass 2: psum[h][k] = sum_j p * a[j][k] ----------------
  float pacc = 0.f;  // thread owns (h, k=l)
  for (int tile = 0; tile < NN / TJ; ++tile) {
    int jbase = tile * TJ;
    __syncthreads();
    {
      const float4* src = (const float4*)(adj + ((size_t)bi * NN + jbase) * NE);
#pragma unroll
      for (int sIdx = 0; sIdx < 4; ++sIdx) {
        int f = t + sIdx * 512;
        float4 v = src[f];
        int jl = f >> 4, k4 = (f & 15) * 4;
        s.a_t[k4 + 0][jl] = v.x;
        s.a_t[k4 + 1][jl] = v.y;
        s.a_t[k4 + 2][jl] = v.z;
        s.a_t[k4 + 3][jl] = v.w;
      }
    }
    __syncthreads();
    const float* prow = &s.sc[h][jbase];
#pragma unroll 8
    for (int j = 0; j < TJ; ++j) pacc += prow[j] * s.a_t[l][j];
  }
  s.psum[h][l] = pacc;
  __syncthreads();

  // ---------------- epilogue: out = sum_j p nv_j + Ve psum ----------------
  if (t < ND) {
    int c = t;
    int hc = c >> 4;
    float acc = 0.f;
    const float* nvb = nv + (size_t)b * NN * ND + c;
#pragma unroll 4
    for (int j = 0; j < NN; ++j) acc += s.sc[hc][j] * nvb[(size_t)j * ND];
    const float4* wr = (const float4*)(wev + c * NE);
    const float* ps = s.psum[hc];
#pragma unroll
    for (int k4 = 0; k4 < NE / 4; ++k4) {
      float4 w4 = wr[k4];
      acc += w4.x * ps[4 * k4] + w4.y * ps[4 * k4 + 1] +
             w4.z * ps[4 * k4 + 2] + w4.w * ps[4 * k4 + 3];
    }
    // channel c -> (h=c/16, d=c%16); output position d*HEADS + h
    att[(size_t)bi * ND + (c & 15) * NHD + hc] = acc;
  }
}

// ---------------- K3: nfc1 + LN1 + FFN + LN2, serial LN reductions ---------
struct FfnS {
  float atts[ND];
  float tvb[ND];
  float x1[ND];
  float hb[NHID];
  float stats[2];  // mean, rstd
};

__global__ void k_node_ffn(const float* __restrict__ x,
                           const float* __restrict__ att,
                           const float* __restrict__ w1, const float* __restrict__ b1,
                           const float* __restrict__ g1, const float* __restrict__ bb1,
                           const float* __restrict__ w2, const float* __restrict__ b2,
                           const float* __restrict__ w3, const float* __restrict__ b3,
                           const float* __restrict__ g2, const float* __restrict__ bb2,
                           float* __restrict__ xout) {
  __shared__ FfnS s;
  int row = blockIdx.x;
  int tid = threadIdx.x;  // 256
  if (tid < ND) s.atts[tid] = att[row * ND + tid];
  __syncthreads();

  if (tid < ND) {
    float acc = b1[tid];
    for (int k = 0; k < ND; ++k) acc += s.atts[k] * w1[tid * ND + k];
    s.tvb[tid] = x[row * ND + tid] + acc;
  }
  __syncthreads();
  if (tid == 0) {
    float m = 0.f;
    for (int k = 0; k < ND; ++k) m += s.tvb[k];
    m *= (1.f / ND);
    float v = 0.f;
    for (int k = 0; k < ND; ++k) { float d = s.tvb[k] - m; v += d * d; }
    s.stats[0] = m;
    s.stats[1] = rsqrtf(v * (1.f / ND) + LN_EPS);
  }
  __syncthreads();
  if (tid < ND)
    s.x1[tid] = (s.tvb[tid] - s.stats[0]) * s.stats[1] * g1[tid] + bb1[tid];
  __syncthreads();

  {
    float acc = b2[tid];
    for (int k = 0; k < ND; ++k) acc += s.x1[k] * w2[tid * ND + k];
    s.hb[tid] = fmaxf(acc, 0.f);
  }
  __syncthreads();

  if (tid < ND) {
    float acc = b3[tid];
    for (int k = 0; k < NHID; ++k) acc += s.hb[k] * w3[tid * NHID + k];
    s.tvb[tid] = s.x1[tid] + acc;
  }
  __syncthreads();
  if (tid == 0) {
    float m = 0.f;
    for (int k = 0; k < ND; ++k) m += s.tvb[k];
    m *= (1.f / ND);
    float v = 0.f;
    for (int k = 0; k < ND; ++k) { float d = s.tvb[k] - m; v += d * d; }
    s.stats[0] = m;
    s.stats[1] = rsqrtf(v * (1.f / ND) + LN_EPS);
  }
  __syncthreads();
  if (tid < ND) {
    float o = (s.tvb[tid] - s.stats[0]) * s.stats[1] * g2[tid] + bb2[tid];
    xout[row * ND + tid] = o;  // FLOAT32 output
  }
}

// ---------------- K4: edge update stage 1, block per (b,i), wave per j ------
// x2 (post-LN2 node features) read from the f32 x-output region of d_out.
struct E1S {
  u32 e1p[EH1 / 2][NE];  // 48KB bf16-pair weights
  u32 e2p[NE / 2][NE];   // 8KB
  float ua[4][EH1];
  float hbf[4][NE];
  float xi[ND];
};

__global__ void k_edge1(const float* __restrict__ adj,
                        const float* __restrict__ xq,
                        const float* __restrict__ w1, const float* __restrict__ b1,
                        const float* __restrict__ w2, const float* __restrict__ b2,
                        const float* __restrict__ g, const float* __restrict__ bb,
                        float* __restrict__ adj1out) {
  __shared__ E1S s;
  int bi = blockIdx.x;
  int b = bi / NN, i = bi % NN;
  int tid = threadIdx.x;  // 256
  int w = tid >> 6, l = tid & 63;

  const float2* w1f = (const float2*)w1;
  for (int p = tid; p < NE * (EH1 / 2); p += 256) {
    int li = p / (EH1 / 2), k2 = p % (EH1 / 2);
    float2 v = w1f[p];
    s.e1p[k2][li] = packbf(v.x, v.y);
  }
  const float2* w2f = (const float2*)w2;
  for (int p = tid; p < NE * (NE / 2); p += 256) {
    int c = p / (NE / 2), l2 = p % (NE / 2);
    float2 v = w2f[p];
    s.e2p[l2][c] = packbf(v.x, v.y);
  }
  if (tid < ND) s.xi[tid] = xq[bi * ND + tid];
  __syncthreads();

  s.ua[w][256 + l] = s.xi[l];  // tgt x_i, constant per block
  s.ua[w][320 + l] = s.xi[64 + l];
  float bias1 = b1[l];
  float bias2 = b2[l];
  float gl = g[l];
  float bl = bb[l];

  for (int j = w; j < NN; j += 4) {
    float aij = adj[((size_t)bi * NN + j) * NE + l];
    s.ua[w][l] = aij;
    s.ua[w][64 + l] = adj[((size_t)(b * NN + j) * NN + i) * NE + l];
    s.ua[w][128 + l] = xq[(b * NN + j) * ND + l];  // src x_j
    s.ua[w][192 + l] = xq[(b * NN + j) * ND + 64 + l];
    float acc = bias1;
    const float2* ua2 = (const float2*)s.ua[w];
#pragma unroll 4
    for (int k2 = 0; k2 < EH1 / 2; ++k2) {
      float2 uv = ua2[k2];
      u32 wp = s.e1p[k2][l];
      acc += uv.x * bflo(wp) + uv.y * bfhi(wp);
    }
    float h = fmaxf(acc, 0.f);
    s.hbf[w][l] = h;
    float r = bias2;
    const float2* h2 = (const float2*)s.hbf[w];
#pragma unroll 4
    for (int l2 = 0; l2 < NE / 2; ++l2) {
      float2 hv = h2[l2];
      u32 wp = s.e2p[l2][l];
      r += hv.x * bflo(wp) + hv.y * bfhi(wp);
    }
    float tv = aij + r;
    float mean = wsum64(tv) * (1.f / NE);
    float dv = tv - mean;
    float var = wsum64(dv * dv) * (1.f / NE);
    float o = dv * rsqrtf(var + LN_EPS) * gl + bl;
    adj1out[((size_t)bi * NN + j) * NE + l] = o;  // FLOAT32 output
  }
}

// ---------------- K5: edge update stage 2 (in-place on d_out adj, f32) -----
struct E2S {
  u32 e3p[NE / 2][EH2];  // 16KB
  u32 e4p[EH2 / 2][NE];  // 16KB
  float tb[8][NE];
  float h2b[8][EH2];
};

__global__ void k_edge2(float* __restrict__ adjio,
                        const float* __restrict__ w3, const float* __restrict__ b3,
                        const float* __restrict__ w4, const float* __restrict__ b4,
                        const float* __restrict__ g, const float* __restrict__ bb) {
  __shared__ E2S s;
  int bi = blockIdx.x;
  int tid = threadIdx.x;  // 512
  int w = tid >> 6, l = tid & 63;

  const float2* w3f = (const float2*)w3;
  for (int p = tid; p < EH2 * (NE / 2); p += 512) {
    int uu = p / (NE / 2), k2 = p % (NE / 2);
    float2 v = w3f[p];
    s.e3p[k2][uu] = packbf(v.x, v.y);
  }
  const float2* w4f = (const float2*)w4;
  for (int p = tid; p < NE * (EH2 / 2); p += 512) {
    int c = p / (EH2 / 2), u2 = p % (EH2 / 2);
    float2 v = w4f[p];
    s.e4p[u2][c] = packbf(v.x, v.y);
  }
  __syncthreads();

  float b3a = b3[2 * l], b3b = b3[2 * l + 1];
  float bias4 = b4[l];
  float gl = g[l], bl = bb[l];

  for (int j = w; j < NN; j += 8) {
    size_t off = ((size_t)bi * NN + j) * NE + l;
    float t0 = adjio[off];
    s.tb[w][l] = t0;
    float a0 = b3a, a1 = b3b;
    const float2* t2 = (const float2*)s.tb[w];
#pragma unroll 4
    for (int k2 = 0; k2 < NE / 2; ++k2) {
      float2 tv = t2[k2];
      uint2 wp = *(const uint2*)&s.e3p[k2][2 * l];
      a0 += tv.x * bflo(wp.x) + tv.y * bfhi(wp.x);
      a1 += tv.x * bflo(wp.y) + tv.y * bfhi(wp.y);
    }
    s.h2b[w][2 * l] = fmaxf(a0, 0.f);
    s.h2b[w][2 * l + 1] = fmaxf(a1, 0.f);
    float r = bias4;
    const float2* hh = (const float2*)s.h2b[w];
#pragma unroll 4
    for (int u2 = 0; u2 < EH2 / 2; ++u2) {
      float2 hv = hh[u2];
      u32 wp = s.e4p[u2][l];
      r += hv.x * bflo(wp) + hv.y * bfhi(wp);
    }
    float tv = t0 + r;
    float mean = wsum64(tv) * (1.f / NE);
    float dv = tv - mean;
    float var = wsum64(dv * dv) * (1.f / NE);
    float o = dv * rsqrtf(var + LN_EPS) * gl + bl;
    adjio[off] = o;  // FLOAT32 output
  }
}

extern "C" void kernel_launch(void* const* d_in, const int* in_sizes, int n_in,
                              void* d_out, int out_size, void* d_ws, size_t ws_size,
                              hipStream_t stream) {
  (void)in_sizes; (void)n_in; (void)out_size; (void)d_ws; (void)ws_size;
  // setup_inputs() dict insertion order (confirmed: in_sizes[0]==98304, R5)
  const float* x      = (const float*)d_in[0];
  const float* adj    = (const float*)d_in[1];
  const float* wnq    = (const float*)d_in[2];
  const float* wnk    = (const float*)d_in[3];
  const float* wnv    = (const float*)d_in[4];
  const float* weq    = (const float*)d_in[5];
  const float* wek    = (const float*)d_in[6];
  const float* wev    = (const float*)d_in[7];
  const float* nfc1_w = (const float*)d_in[8];
  const float* nfc1_b = (const float*)d_in[9];
  const float* ln1_g  = (const float*)d_in[10];
  const float* ln1_b  = (const float*)d_in[11];
  const float* nfc2_w = (const float*)d_in[12];
  const float* nfc2_b = (const float*)d_in[13];
  const float* nfc3_w = (const float*)d_in[14];
  const float* nfc3_b = (const float*)d_in[15];
  const float* ln2_g  = (const float*)d_in[16];
  const float* ln2_b  = (const float*)d_in[17];
  const float* efc1_w = (const float*)d_in[18];
  const float* efc1_b = (const float*)d_in[19];
  const float* efc2_w = (const float*)d_in[20];
  const float* efc2_b = (const float*)d_in[21];
  const float* eln1_g = (const float*)d_in[22];
  const float* eln1_b = (const float*)d_in[23];
  const float* efc3_w = (const float*)d_in[24];
  const float* efc3_b = (const float*)d_in[25];
  const float* efc4_w = (const float*)d_in[26];
  const float* efc4_b = (const float*)d_in[27];
  const float* eln2_g = (const float*)d_in[28];
  const float* eln2_b = (const float*)d_in[29];

  float* outf = (float*)d_out;          // FLOAT32 output buffer: [x ; adj]
  float* outadj = outf + XOUT_ELEMS;

  // f32 scratch in the tail of the adj-output region (dead until k_edge1,
  // by which time nq/nk/nv/att are all consumed). No d_ws usage.
  float* scratch = outf + OUT_ELEMS - SCRATCH_F32;
  float* nq  = scratch;
  float* nk  = scratch + XOUT_ELEMS;
  float* nv  = scratch + 2 * XOUT_ELEMS;
  float* att = scratch + 3 * XOUT_ELEMS;

  k_node_qkv<<<NB * NN, 128, 0, stream>>>(x, wnq, wnk, wnv, nq, nk, nv);
  k_attn<<<NB * NN, 512, 0, stream>>>(adj, weq, wek, wev, nq, nk, nv, att);
  k_node_ffn<<<NB * NN, 256, 0, stream>>>(x, att, nfc1_w, nfc1_b, ln1_g, ln1_b,
                                          nfc2_w, nfc2_b, nfc3_w, nfc3_b,
                                          ln2_g, ln2_b, outf);
  k_edge1<<<NB * NN, 256, 0, stream>>>(adj, outf, efc1_w, efc1_b, efc2_w, efc2_b,
                                       eln1_g, eln1_b, outadj);
  k_edge2<<<NB * NN, 512, 0, stream>>>(outadj, efc3_w, efc3_b, efc4_w, efc4_b,
                                       eln2_g, eln2_b);
}

// Round 2
// 755.629 us; speedup vs baseline: 11.9575x; 2.6594x over previous
//
#include <hip/hip_runtime.h>
#include <hip/hip_bf16.h>

typedef unsigned short u16;
typedef unsigned int u32;

#define NB 2
#define NN 384
#define ND 128
#define NE 64
#define NHD 8
#define NHID 256
#define EH1 384
#define EH2 128
#define LN_EPS 1e-5f
#define ATT_SCALE 0.17677669529663687f  // 1/sqrt(NODE_HIDDEN//HEADS)=1/sqrt(32)

#define XOUT_ELEMS (NB * NN * ND)                 // 98304
#define ADJ_ELEMS ((size_t)NB * NN * NN * NE)     // 18874368
#define OUT_ELEMS (XOUT_ELEMS + ADJ_ELEMS)        // 18972672 f32 elements
// f32 scratch carved from the TAIL of the adj-output region (dead until
// k_edge1 writes it, by which time scratch is fully consumed).
#define SCRATCH_F32 (4 * XOUT_ELEMS)              // nq,nk,nv,att

typedef __attribute__((ext_vector_type(4))) float f32x4;
typedef __attribute__((ext_vector_type(8))) short s16x8;
#define MFMA16(a, b, c) __builtin_amdgcn_mfma_f32_16x16x32_bf16(a, b, c, 0, 0, 0)

__device__ __forceinline__ float bflo(u32 u) {
  return __builtin_bit_cast(float, u << 16);
}
__device__ __forceinline__ float bfhi(u32 u) {
  return __builtin_bit_cast(float, u & 0xffff0000u);
}
__device__ __forceinline__ u16 bfr(float f) {
  return __builtin_bit_cast(u16, __float2bfloat16(f));
}
__device__ __forceinline__ float bfu(u16 h) {
  return __builtin_bit_cast(float, ((u32)h) << 16);
}
__device__ __forceinline__ u32 packbf(float a, float b) {
  return (u32)bfr(a) | ((u32)bfr(b) << 16);
}
__device__ __forceinline__ float wsum64(float v) {
#pragma unroll
  for (int o = 32; o > 0; o >>= 1) v += __shfl_xor(v, o, 64);
  return v;
}
__device__ __forceinline__ float wmax64(float v) {
#pragma unroll
  for (int o = 32; o > 0; o >>= 1) v = fmaxf(v, __shfl_xor(v, o, 64));
  return v;
}

// convert 8 consecutive f32 -> one bf16 weight fragment (short8)
__device__ __forceinline__ s16x8 cvt_frag(const float* p) {
  float4 a = *(const float4*)p;
  float4 c = *(const float4*)(p + 4);
  s16x8 r;
  r[0] = (short)bfr(a.x); r[1] = (short)bfr(a.y);
  r[2] = (short)bfr(a.z); r[3] = (short)bfr(a.w);
  r[4] = (short)bfr(c.x); r[5] = (short)bfr(c.y);
  r[6] = (short)bfr(c.z); r[7] = (short)bfr(c.w);
  return r;
}

// convert 8 consecutive f32 -> hi/lo bf16 pairs (16B each)
__device__ __forceinline__ void cvt8_hl(const float* p, uint4& hi, uint4& lo) {
  float4 a = *(const float4*)p;
  float4 c = *(const float4*)(p + 4);
  float v[8] = {a.x, a.y, a.z, a.w, c.x, c.y, c.z, c.w};
  u32 hw[4], lw[4];
#pragma unroll
  for (int e = 0; e < 4; ++e) {
    u16 h0 = bfr(v[2 * e]), h1 = bfr(v[2 * e + 1]);
    u16 l0 = bfr(v[2 * e] - bfu(h0));
    u16 l1 = bfr(v[2 * e + 1] - bfu(h1));
    hw[e] = (u32)h0 | ((u32)h1 << 16);
    lw[e] = (u32)l0 | ((u32)l1 << 16);
  }
  hi.x = hw[0]; hi.y = hw[1]; hi.z = hw[2]; hi.w = hw[3];
  lo.x = lw[0]; lo.y = lw[1]; lo.z = lw[2]; lo.w = lw[3];
}

// ---------------- K1: nq/nk/nv = x @ w{q,k,v}.T (f32, plain) ----------------
__global__ void k_node_qkv(const float* __restrict__ x,
                           const float* __restrict__ wq,
                           const float* __restrict__ wk,
                           const float* __restrict__ wv,
                           float* __restrict__ nq, float* __restrict__ nk,
                           float* __restrict__ nv) {
  int row = blockIdx.x;  // b*N+i
  int t = threadIdx.x;   // 128
  __shared__ float xs[ND];
  xs[t] = x[row * ND + t];
  __syncthreads();
  float aq = 0.f, ak = 0.f, av = 0.f;
  for (int k = 0; k < ND; ++k) {
    float xv = xs[k];
    aq += xv * wq[t * ND + k];
    ak += xv * wk[t * ND + k];
    av += xv * wv[t * ND + k];
  }
  nq[row * ND + t] = aq;
  nk[row * ND + t] = ak;
  nv[row * ND + t] = av;
}

// ---------------- K2: attention, LDS-tiled, wave-per-head ----------------
#define TJ 128
struct AttnS {
  u32 wq_p[NE][64];      // 16KB  [k][c2] packs channels (2c2, 2c2+1)
  u32 wk_p[NE][64];      // 16KB
  float a_t[NE][TJ + 1]; // 33024B transposed adj tile: a_t[k][jloc]
  float sc[NHD][NN];     // 12KB  scores -> probs
  float psum[NHD][NE];   // 2KB
};

__global__ void __launch_bounds__(512) k_attn(
    const float* __restrict__ adj,
    const float* __restrict__ weq,
    const float* __restrict__ wek,
    const float* __restrict__ wev,
    const float* __restrict__ nq,
    const float* __restrict__ nk,
    const float* __restrict__ nv,
    float* __restrict__ att) {
  __shared__ AttnS s;
  int bi = blockIdx.x;     // b*N + i
  int b = bi / NN;
  int t = threadIdx.x;     // 512
  int h = t >> 6;          // wave = head
  int l = t & 63;
  int h8 = h * 8;

  for (int p = t; p < NE * 64; p += 512) {
    int c2 = p >> 6, k = p & 63;
    s.wq_p[k][c2] = packbf(weq[(2 * c2) * NE + k], weq[(2 * c2 + 1) * NE + k]);
    s.wk_p[k][c2] = packbf(wek[(2 * c2) * NE + k], wek[(2 * c2 + 1) * NE + k]);
  }

  float nqv[16];
  {
    const float* nqr = nq + (size_t)bi * ND + h * 16;
#pragma unroll
    for (int d = 0; d < 16; ++d) nqv[d] = nqr[d];
  }
  __syncthreads();

  // ---------------- pass 1: scores ----------------
  for (int tile = 0; tile < NN / TJ; ++tile) {
    int jbase = tile * TJ;
    __syncthreads();
    {
      const float4* src = (const float4*)(adj + ((size_t)bi * NN + jbase) * NE);
#pragma unroll
      for (int sIdx = 0; sIdx < 4; ++sIdx) {
        int f = t + sIdx * 512;
        float4 v = src[f];
        int jl = f >> 4, k4 = (f & 15) * 4;
        s.a_t[k4 + 0][jl] = v.x;
        s.a_t[k4 + 1][jl] = v.y;
        s.a_t[k4 + 2][jl] = v.z;
        s.a_t[k4 + 3][jl] = v.w;
      }
    }
    __syncthreads();

    float eq0[16], ek0[16], eq1[16], ek1[16];
#pragma unroll
    for (int d = 0; d < 16; ++d) {
      eq0[d] = nqv[d]; eq1[d] = nqv[d];
      ek0[d] = 0.f;    ek1[d] = 0.f;
    }
#pragma unroll 2
    for (int k = 0; k < NE; ++k) {
      float a0 = s.a_t[k][l];
      float a1 = s.a_t[k][l + 64];
      uint4 wqa = *(const uint4*)&s.wq_p[k][h8];
      uint4 wqb = *(const uint4*)&s.wq_p[k][h8 + 4];
      uint4 wka = *(const uint4*)&s.wk_p[k][h8];
      uint4 wkb = *(const uint4*)&s.wk_p[k][h8 + 4];
      u32 wq8[8] = {wqa.x, wqa.y, wqa.z, wqa.w, wqb.x, wqb.y, wqb.z, wqb.w};
      u32 wk8[8] = {wka.x, wka.y, wka.z, wka.w, wkb.x, wkb.y, wkb.z, wkb.w};
#pragma unroll
      for (int d2 = 0; d2 < 8; ++d2) {
        float ql = bflo(wq8[d2]), qh = bfhi(wq8[d2]);
        float kl = bflo(wk8[d2]), kh = bfhi(wk8[d2]);
        eq0[2 * d2]     += a0 * ql;
        eq0[2 * d2 + 1] += a0 * qh;
        eq1[2 * d2]     += a1 * ql;
        eq1[2 * d2 + 1] += a1 * qh;
        ek0[2 * d2]     += a0 * kl;
        ek0[2 * d2 + 1] += a0 * kh;
        ek1[2 * d2]     += a1 * kl;
        ek1[2 * d2 + 1] += a1 * kh;
      }
    }
    int j0 = jbase + l, j1 = j0 + 64;
    const float* nkr0 = nk + ((size_t)b * NN + j0) * ND + h * 16;
    const float* nkr1 = nk + ((size_t)b * NN + j1) * ND + h * 16;
    float s0 = 0.f, s1 = 0.f;
#pragma unroll
    for (int d = 0; d < 16; ++d) {
      s0 += eq0[d] * (nkr0[d] + ek0[d]);
      s1 += eq1[d] * (nkr1[d] + ek1[d]);
    }
    s.sc[h][j0] = s0 * ATT_SCALE;
    s.sc[h][j1] = s1 * ATT_SCALE;
  }
  __syncthreads();

  // ---------------- softmax: wave h owns row h ----------------
  {
    float vals[NN / 64];
    float m = -1e30f;
#pragma unroll
    for (int r = 0; r < NN / 64; ++r) {
      vals[r] = s.sc[h][l + 64 * r];
      m = fmaxf(m, vals[r]);
    }
    m = wmax64(m);
    float sum = 0.f;
#pragma unroll
    for (int r = 0; r < NN / 64; ++r) {
      vals[r] = __expf(vals[r] - m);
      sum += vals[r];
    }
    sum = wsum64(sum);
    float rinv = 1.f / sum;
#pragma unroll
    for (int r = 0; r < NN / 64; ++r) s.sc[h][l + 64 * r] = vals[r] * rinv;
  }
  __syncthreads();

  // ---------------- pass 2: psum[h][k] = sum_j p * a[j][k] ----------------
  float pacc = 0.f;  // thread owns (h, k=l)
  for (int tile = 0; tile < NN / TJ; ++tile) {
    int jbase = tile * TJ;
    __syncthreads();
    {
      const float4* src = (const float4*)(adj + ((size_t)bi * NN + jbase) * NE);
#pragma unroll
      for (int sIdx = 0; sIdx < 4; ++sIdx) {
        int f = t + sIdx * 512;
        float4 v = src[f];
        int jl = f >> 4, k4 = (f & 15) * 4;
        s.a_t[k4 + 0][jl] = v.x;
        s.a_t[k4 + 1][jl] = v.y;
        s.a_t[k4 + 2][jl] = v.z;
        s.a_t[k4 + 3][jl] = v.w;
      }
    }
    __syncthreads();
    const float* prow = &s.sc[h][jbase];
#pragma unroll 8
    for (int j = 0; j < TJ; ++j) pacc += prow[j] * s.a_t[l][j];
  }
  s.psum[h][l] = pacc;
  __syncthreads();

  // ---------------- epilogue: out = sum_j p nv_j + Ve psum ----------------
  if (t < ND) {
    int c = t;
    int hc = c >> 4;
    float acc = 0.f;
    const float* nvb = nv + (size_t)b * NN * ND + c;
#pragma unroll 4
    for (int j = 0; j < NN; ++j) acc += s.sc[hc][j] * nvb[(size_t)j * ND];
    const float4* wr = (const float4*)(wev + c * NE);
    const float* ps = s.psum[hc];
#pragma unroll
    for (int k4 = 0; k4 < NE / 4; ++k4) {
      float4 w4 = wr[k4];
      acc += w4.x * ps[4 * k4] + w4.y * ps[4 * k4 + 1] +
             w4.z * ps[4 * k4 + 2] + w4.w * ps[4 * k4 + 3];
    }
    att[(size_t)bi * ND + (c & 15) * NHD + hc] = acc;
  }
}

// ---------------- K3: nfc1 + LN1 + FFN + LN2, serial LN reductions ---------
struct FfnS {
  float atts[ND];
  float tvb[ND];
  float x1[ND];
  float hb[NHID];
  float stats[2];  // mean, rstd
};

__global__ void k_node_ffn(const float* __restrict__ x,
                           const float* __restrict__ att,
                           const float* __restrict__ w1, const float* __restrict__ b1,
                           const float* __restrict__ g1, const float* __restrict__ bb1,
                           const float* __restrict__ w2, const float* __restrict__ b2,
                           const float* __restrict__ w3, const float* __restrict__ b3,
                           const float* __restrict__ g2, const float* __restrict__ bb2,
                           float* __restrict__ xout) {
  __shared__ FfnS s;
  int row = blockIdx.x;
  int tid = threadIdx.x;  // 256
  if (tid < ND) s.atts[tid] = att[row * ND + tid];
  __syncthreads();

  if (tid < ND) {
    float acc = b1[tid];
    for (int k = 0; k < ND; ++k) acc += s.atts[k] * w1[tid * ND + k];
    s.tvb[tid] = x[row * ND + tid] + acc;
  }
  __syncthreads();
  if (tid == 0) {
    float m = 0.f;
    for (int k = 0; k < ND; ++k) m += s.tvb[k];
    m *= (1.f / ND);
    float v = 0.f;
    for (int k = 0; k < ND; ++k) { float d = s.tvb[k] - m; v += d * d; }
    s.stats[0] = m;
    s.stats[1] = rsqrtf(v * (1.f / ND) + LN_EPS);
  }
  __syncthreads();
  if (tid < ND)
    s.x1[tid] = (s.tvb[tid] - s.stats[0]) * s.stats[1] * g1[tid] + bb1[tid];
  __syncthreads();

  {
    float acc = b2[tid];
    for (int k = 0; k < ND; ++k) acc += s.x1[k] * w2[tid * ND + k];
    s.hb[tid] = fmaxf(acc, 0.f);
  }
  __syncthreads();

  if (tid < ND) {
    float acc = b3[tid];
    for (int k = 0; k < NHID; ++k) acc += s.hb[k] * w3[tid * NHID + k];
    s.tvb[tid] = s.x1[tid] + acc;
  }
  __syncthreads();
  if (tid == 0) {
    float m = 0.f;
    for (int k = 0; k < ND; ++k) m += s.tvb[k];
    m *= (1.f / ND);
    float v = 0.f;
    for (int k = 0; k < ND; ++k) { float d = s.tvb[k] - m; v += d * d; }
    s.stats[0] = m;
    s.stats[1] = rsqrtf(v * (1.f / ND) + LN_EPS);
  }
  __syncthreads();
  if (tid < ND) {
    float o = (s.tvb[tid] - s.stats[0]) * s.stats[1] * g2[tid] + bb2[tid];
    xout[row * ND + tid] = o;  // FLOAT32 output
  }
}

// ---------------- K4: edge stage 1 via MFMA, hi/lo bf16 split --------------
// Per block (b,i), 12 M-tiles of 32 j-rows:
//   layer1: [32 x 384] @ W1[64 x 384]^T  -> relu -> H [32 x 64]
//   layer2: H @ W2[64 x 64]^T ; residual + LN over 64 cols.
// Activations split a = hi + lo (bf16 each) -> 2 MFMAs preserve f32xbf16
// numerics. Weights converted once per block into per-wave register frags.
// LDS tiles XOR-swizzled (byte ^= (row&7)<<4) for conflict-free ds_read_b128.
#define EMT 32

struct E1M {
  u16 Ahi[EMT][EH1];   // 24KB swizzled, row stride 768B
  u16 Alo[EMT][EH1];   // 24KB
  u16 Hhi[EMT][NE];    // 4KB swizzled, row stride 128B
  u16 Hlo[EMT][NE];    // 4KB ; Hhi+Hlo reused as f32 tvb[32][64] for LN
};

__global__ void __launch_bounds__(512) k_edge1(
    const float* __restrict__ adj, const float* __restrict__ xq,
    const float* __restrict__ w1, const float* __restrict__ b1,
    const float* __restrict__ w2, const float* __restrict__ b2,
    const float* __restrict__ g, const float* __restrict__ bb,
    float* __restrict__ adj1out) {
  __shared__ E1M s;
  int bi = blockIdx.x;
  int b = bi / NN, i = bi % NN;
  int t = threadIdx.x;      // 512
  int w = t >> 6, l = t & 63;
  int m16 = (w & 1) * 16;   // wave's M sub-tile base
  int n16 = (w >> 1) * 16;  // wave's N sub-tile base
  int lr = l & 15, lk = l >> 4;

  // per-wave weight fragments in registers (f32 -> bf16 once per block)
  s16x8 B1[12], B2[2];
  {
    const float* wr = w1 + (size_t)(n16 + lr) * EH1 + lk * 8;
#pragma unroll
    for (int ks = 0; ks < 12; ++ks) B1[ks] = cvt_frag(wr + ks * 32);
    const float* w2r = w2 + (size_t)(n16 + lr) * NE + lk * 8;
#pragma unroll
    for (int ks = 0; ks < 2; ++ks) B2[ks] = cvt_frag(w2r + ks * 32);
  }
  float bias1 = b1[n16 + lr];
  float bias2 = b2[n16 + lr];
  float gl = g[l], bl = bb[l];

  for (int mt = 0; mt < NN / EMT; ++mt) {
    int jbase = mt * EMT;
    __syncthreads();
    // stage ua tile: 32 rows x 48 x 16B units (hi/lo)
    for (int p = t; p < EMT * 48; p += 512) {
      int row = p / 48, u = p % 48;
      const float* src;
      if (u < 8)
        src = adj + ((size_t)bi * NN + jbase + row) * NE + u * 8;
      else if (u < 16)
        src = adj + ((size_t)(b * NN + jbase + row) * NN + i) * NE + (u - 8) * 8;
      else if (u < 32)
        src = xq + (size_t)(b * NN + jbase + row) * ND + (u - 16) * 8;
      else
        src = xq + (size_t)bi * ND + (u - 32) * 8;
      uint4 hi, lo;
      cvt8_hl(src, hi, lo);
      int byt = (row * 768 + u * 16) ^ ((row & 7) << 4);
      *(uint4*)((char*)s.Ahi + byt) = hi;
      *(uint4*)((char*)s.Alo + byt) = lo;
    }
    __syncthreads();

    // layer1
    f32x4 acc = {0.f, 0.f, 0.f, 0.f};
    int arow = m16 + lr;
    int aswz = (arow & 7) << 4;
#pragma unroll
    for (int ks = 0; ks < 12; ++ks) {
      int byt = (arow * 768 + ks * 64 + lk * 16) ^ aswz;
      s16x8 ah = *(const s16x8*)((const char*)s.Ahi + byt);
      s16x8 al = *(const s16x8*)((const char*)s.Alo + byt);
      acc = MFMA16(ah, B1[ks], acc);
      acc = MFMA16(al, B1[ks], acc);
    }
#pragma unroll
    for (int r = 0; r < 4; ++r) {
      float hv = fmaxf(acc[r] + bias1, 0.f);
      u16 hh = bfr(hv);
      u16 hl = bfr(hv - bfu(hh));
      int row = m16 + lk * 4 + r;
      int byt = (row * 128 + (n16 + lr) * 2) ^ ((row & 7) << 4);
      *(u16*)((char*)s.Hhi + byt) = hh;
      *(u16*)((char*)s.Hlo + byt) = hl;
    }
    __syncthreads();

    // layer2
    f32x4 acc2 = {0.f, 0.f, 0.f, 0.f};
#pragma unroll
    for (int ks = 0; ks < 2; ++ks) {
      int byt = (arow * 128 + ks * 64 + lk * 16) ^ aswz;
      s16x8 ah = *(const s16x8*)((const char*)s.Hhi + byt);
      s16x8 al = *(const s16x8*)((const char*)s.Hlo + byt);
      acc2 = MFMA16(ah, B2[ks], acc2);
      acc2 = MFMA16(al, B2[ks], acc2);
    }
    __syncthreads();  // H reads done -> reuse as f32 tv buffer
    float* tvb = (float*)s.Hhi;
#pragma unroll
    for (int r = 0; r < 4; ++r) {
      int row = m16 + lk * 4 + r;
      int col = n16 + lr;
      int abyt = (row * 768 + col * 2) ^ ((row & 7) << 4);
      float aorig = bfu(*(const u16*)((const char*)s.Ahi + abyt)) +
                    bfu(*(const u16*)((const char*)s.Alo + abyt));
      tvb[row * NE + col] = aorig + acc2[r] + bias2;
    }
    __syncthreads();
    // LN: wave w handles rows w*4..w*4+3, lane = col
#pragma unroll
    for (int rr = 0; rr < EMT / 8; ++rr) {
      int row = w * (EMT / 8) + rr;
      float tv = tvb[row * NE + l];
      float mean = wsum64(tv) * (1.f / NE);
      float dv = tv - mean;
      float var = wsum64(dv * dv) * (1.f / NE);
      float o = dv * rsqrtf(var + LN_EPS) * gl + bl;
      adj1out[((size_t)bi * NN + jbase + row) * NE + l] = o;
    }
  }
}

// ---------------- K5: edge stage 2 via MFMA (in-place on d_out adj) --------
struct E2M {
  u16 Ahi[EMT][NE];    // 4KB swizzled, row stride 128B
  u16 Alo[EMT][NE];    // 4KB
  u16 Hhi[EMT][EH2];   // 8KB swizzled, row stride 256B ; reused as f32 tvb
  u16 Hlo[EMT][EH2];   // 8KB
};

__global__ void __launch_bounds__(512) k_edge2(
    float* __restrict__ adjio,
    const float* __restrict__ w3, const float* __restrict__ b3,
    const float* __restrict__ w4, const float* __restrict__ b4,
    const float* __restrict__ g, const float* __restrict__ bb) {
  __shared__ E2M s;
  int bi = blockIdx.x;
  int t = threadIdx.x;      // 512
  int w = t >> 6, l = t & 63;
  int m16 = (w & 1) * 16;
  int nb = (w >> 1) * 2;    // layer3 n16 pair base (0,2,4,6)
  int n16 = (w >> 1) * 16;  // layer4 col base
  int lr = l & 15, lk = l >> 4;

  s16x8 B3[2][2], B4[4];
  {
#pragma unroll
    for (int n = 0; n < 2; ++n) {
      const float* wr = w3 + (size_t)((nb + n) * 16 + lr) * NE + lk * 8;
#pragma unroll
      for (int ks = 0; ks < 2; ++ks) B3[n][ks] = cvt_frag(wr + ks * 32);
    }
    const float* w4r = w4 + (size_t)(n16 + lr) * EH2 + lk * 8;
#pragma unroll
    for (int ks = 0; ks < 4; ++ks) B4[ks] = cvt_frag(w4r + ks * 32);
  }
  float bias3[2] = {b3[nb * 16 + lr], b3[(nb + 1) * 16 + lr]};
  float bias4 = b4[n16 + lr];
  float gl = g[l], bl = bb[l];

  for (int mt = 0; mt < NN / EMT; ++mt) {
    int jbase = mt * EMT;
    __syncthreads();
    for (int p = t; p < EMT * 8; p += 512) {  // 256 units, threads<256 active
      int row = p >> 3, u = p & 7;
      const float* src = adjio + ((size_t)bi * NN + jbase + row) * NE + u * 8;
      uint4 hi, lo;
      cvt8_hl(src, hi, lo);
      int byt = (row * 128 + u * 16) ^ ((row & 7) << 4);
      *(uint4*)((char*)s.Ahi + byt) = hi;
      *(uint4*)((char*)s.Alo + byt) = lo;
    }
    __syncthreads();

    // layer3: out [32 x 128]
    f32x4 a3[2] = {{0.f, 0.f, 0.f, 0.f}, {0.f, 0.f, 0.f, 0.f}};
    int arow = m16 + lr;
    int aswz = (arow & 7) << 4;
#pragma unroll
    for (int ks = 0; ks < 2; ++ks) {
      int byt = (arow * 128 + ks * 64 + lk * 16) ^ aswz;
      s16x8 ah = *(const s16x8*)((const char*)s.Ahi + byt);
      s16x8 al = *(const s16x8*)((const char*)s.Alo + byt);
#pragma unroll
      for (int n = 0; n < 2; ++n) {
        a3[n] = MFMA16(ah, B3[n][ks], a3[n]);
        a3[n] = MFMA16(al, B3[n][ks], a3[n]);
      }
    }
#pragma unroll
    for (int n = 0; n < 2; ++n) {
#pragma unroll
      for (int r = 0; r < 4; ++r) {
        float hv = fmaxf(a3[n][r] + bias3[n], 0.f);
        u16 hh = bfr(hv);
        u16 hl = bfr(hv - bfu(hh));
        int row = m16 + lk * 4 + r;
        int byt = (row * 256 + ((nb + n) * 16 + lr) * 2) ^ ((row & 7) << 4);
        *(u16*)((char*)s.Hhi + byt) = hh;
        *(u16*)((char*)s.Hlo + byt) = hl;
      }
    }
    __syncthreads();

    // layer4: out [32 x 64]
    f32x4 a4 = {0.f, 0.f, 0.f, 0.f};
#pragma unroll
    for (int ks = 0; ks < 4; ++ks) {
      int byt = (arow * 256 + ks * 64 + lk * 16) ^ aswz;
      s16x8 ah = *(const s16x8*)((const char*)s.Hhi + byt);
      s16x8 al = *(const s16x8*)((const char*)s.Hlo + byt);
      a4 = MFMA16(ah, B4[ks], a4);
      a4 = MFMA16(al, B4[ks], a4);
    }
    __syncthreads();  // H reads done -> reuse as f32 tv buffer
    float* tvb = (float*)s.Hhi;
#pragma unroll
    for (int r = 0; r < 4; ++r) {
      int row = m16 + lk * 4 + r;
      int col = n16 + lr;
      int abyt = (row * 128 + col * 2) ^ ((row & 7) << 4);
      float aorig = bfu(*(const u16*)((const char*)s.Ahi + abyt)) +
                    bfu(*(const u16*)((const char*)s.Alo + abyt));
      tvb[row * NE + col] = aorig + a4[r] + bias4;
    }
    __syncthreads();
#pragma unroll
    for (int rr = 0; rr < EMT / 8; ++rr) {
      int row = w * (EMT / 8) + rr;
      float tv = tvb[row * NE + l];
      float mean = wsum64(tv) * (1.f / NE);
      float dv = tv - mean;
      float var = wsum64(dv * dv) * (1.f / NE);
      float o = dv * rsqrtf(var + LN_EPS) * gl + bl;
      adjio[((size_t)bi * NN + jbase + row) * NE + l] = o;
    }
  }
}

extern "C" void kernel_launch(void* const* d_in, const int* in_sizes, int n_in,
                              void* d_out, int out_size, void* d_ws, size_t ws_size,
                              hipStream_t stream) {
  (void)in_sizes; (void)n_in; (void)out_size; (void)d_ws; (void)ws_size;
  const float* x      = (const float*)d_in[0];
  const float* adj    = (const float*)d_in[1];
  const float* wnq    = (const float*)d_in[2];
  const float* wnk    = (const float*)d_in[3];
  const float* wnv    = (const float*)d_in[4];
  const float* weq    = (const float*)d_in[5];
  const float* wek    = (const float*)d_in[6];
  const float* wev    = (const float*)d_in[7];
  const float* nfc1_w = (const float*)d_in[8];
  const float* nfc1_b = (const float*)d_in[9];
  const float* ln1_g  = (const float*)d_in[10];
  const float* ln1_b  = (const float*)d_in[11];
  const float* nfc2_w = (const float*)d_in[12];
  const float* nfc2_b = (const float*)d_in[13];
  const float* nfc3_w = (const float*)d_in[14];
  const float* nfc3_b = (const float*)d_in[15];
  const float* ln2_g  = (const float*)d_in[16];
  const float* ln2_b  = (const float*)d_in[17];
  const float* efc1_w = (const float*)d_in[18];
  const float* efc1_b = (const float*)d_in[19];
  const float* efc2_w = (const float*)d_in[20];
  const float* efc2_b = (const float*)d_in[21];
  const float* eln1_g = (const float*)d_in[22];
  const float* eln1_b = (const float*)d_in[23];
  const float* efc3_w = (const float*)d_in[24];
  const float* efc3_b = (const float*)d_in[25];
  const float* efc4_w = (const float*)d_in[26];
  const float* efc4_b = (const float*)d_in[27];
  const float* eln2_g = (const float*)d_in[28];
  const float* eln2_b = (const float*)d_in[29];

  float* outf = (float*)d_out;          // FLOAT32 output buffer: [x ; adj]
  float* outadj = outf + XOUT_ELEMS;

  float* scratch = outf + OUT_ELEMS - SCRATCH_F32;
  float* nq  = scratch;
  float* nk  = scratch + XOUT_ELEMS;
  float* nv  = scratch + 2 * XOUT_ELEMS;
  float* att = scratch + 3 * XOUT_ELEMS;

  k_node_qkv<<<NB * NN, 128, 0, stream>>>(x, wnq, wnk, wnv, nq, nk, nv);
  k_attn<<<NB * NN, 512, 0, stream>>>(adj, weq, wek, wev, nq, nk, nv, att);
  k_node_ffn<<<NB * NN, 256, 0, stream>>>(x, att, nfc1_w, nfc1_b, ln1_g, ln1_b,
                                          nfc2_w, nfc2_b, nfc3_w, nfc3_b,
                                          ln2_g, ln2_b, outf);
  k_edge1<<<NB * NN, 512, 0, stream>>>(adj, outf, efc1_w, efc1_b, efc2_w, efc2_b,
                                       eln1_g, eln1_b, outadj);
  k_edge2<<<NB * NN, 512, 0, stream>>>(outadj, efc3_w, efc3_b, efc4_w, efc4_b,
                                       eln2_g, eln2_b);
}

// Round 3
// 620.442 us; speedup vs baseline: 14.5629x; 1.2179x over previous
//
#include <hip/hip_runtime.h>
#include <hip/hip_bf16.h>

typedef unsigned short u16;
typedef unsigned int u32;

#define NB 2
#define NN 384
#define ND 128
#define NE 64
#define NHD 8
#define NHID 256
#define EH1 384
#define EH2 128
#define LN_EPS 1e-5f
#define ATT_SCALE 0.17677669529663687f  // 1/sqrt(NODE_HIDDEN//HEADS)=1/sqrt(32)

#define XOUT_ELEMS (NB * NN * ND)                 // 98304
#define ADJ_ELEMS ((size_t)NB * NN * NN * NE)     // 18874368
#define OUT_ELEMS (XOUT_ELEMS + ADJ_ELEMS)        // 18972672 f32 elements
// f32 scratch carved from the TAIL of the adj-output region (dead until
// k_edge1 writes it, by which time scratch is fully consumed).
#define SCRATCH_F32 (4 * XOUT_ELEMS)              // nq,nk,nv,att

typedef __attribute__((ext_vector_type(4))) float f32x4;
typedef __attribute__((ext_vector_type(8))) short s16x8;
#define MFMA16(a, b, c) __builtin_amdgcn_mfma_f32_16x16x32_bf16(a, b, c, 0, 0, 0)

__device__ __forceinline__ float bflo(u32 u) {
  return __builtin_bit_cast(float, u << 16);
}
__device__ __forceinline__ float bfhi(u32 u) {
  return __builtin_bit_cast(float, u & 0xffff0000u);
}
__device__ __forceinline__ u16 bfr(float f) {
  return __builtin_bit_cast(u16, __float2bfloat16(f));
}
__device__ __forceinline__ float bfu(u16 h) {
  return __builtin_bit_cast(float, ((u32)h) << 16);
}
__device__ __forceinline__ u32 packbf(float a, float b) {
  return (u32)bfr(a) | ((u32)bfr(b) << 16);
}
__device__ __forceinline__ float wsum64(float v) {
#pragma unroll
  for (int o = 32; o > 0; o >>= 1) v += __shfl_xor(v, o, 64);
  return v;
}
__device__ __forceinline__ float wmax64(float v) {
#pragma unroll
  for (int o = 32; o > 0; o >>= 1) v = fmaxf(v, __shfl_xor(v, o, 64));
  return v;
}

// convert 8 consecutive f32 -> one bf16 weight fragment (short8)
__device__ __forceinline__ s16x8 cvt_frag(const float* p) {
  float4 a = *(const float4*)p;
  float4 c = *(const float4*)(p + 4);
  s16x8 r;
  r[0] = (short)bfr(a.x); r[1] = (short)bfr(a.y);
  r[2] = (short)bfr(a.z); r[3] = (short)bfr(a.w);
  r[4] = (short)bfr(c.x); r[5] = (short)bfr(c.y);
  r[6] = (short)bfr(c.z); r[7] = (short)bfr(c.w);
  return r;
}

// convert 8 consecutive f32 -> hi/lo bf16 pairs (16B each)
__device__ __forceinline__ void cvt8_hl(const float* p, uint4& hi, uint4& lo) {
  float4 a = *(const float4*)p;
  float4 c = *(const float4*)(p + 4);
  float v[8] = {a.x, a.y, a.z, a.w, c.x, c.y, c.z, c.w};
  u32 hw[4], lw[4];
#pragma unroll
  for (int e = 0; e < 4; ++e) {
    u16 h0 = bfr(v[2 * e]), h1 = bfr(v[2 * e + 1]);
    u16 l0 = bfr(v[2 * e] - bfu(h0));
    u16 l1 = bfr(v[2 * e + 1] - bfu(h1));
    hw[e] = (u32)h0 | ((u32)h1 << 16);
    lw[e] = (u32)l0 | ((u32)l1 << 16);
  }
  hi.x = hw[0]; hi.y = hw[1]; hi.z = hw[2]; hi.w = hw[3];
  lo.x = lw[0]; lo.y = lw[1]; lo.z = lw[2]; lo.w = lw[3];
}

// ---------------- K1: nq/nk/nv = x @ w{q,k,v}.T (f32, plain) ----------------
__global__ void k_node_qkv(const float* __restrict__ x,
                           const float* __restrict__ wq,
                           const float* __restrict__ wk,
                           const float* __restrict__ wv,
                           float* __restrict__ nq, float* __restrict__ nk,
                           float* __restrict__ nv) {
  int row = blockIdx.x;  // b*N+i
  int t = threadIdx.x;   // 128
  __shared__ float xs[ND];
  xs[t] = x[row * ND + t];
  __syncthreads();
  float aq = 0.f, ak = 0.f, av = 0.f;
  for (int k = 0; k < ND; ++k) {
    float xv = xs[k];
    aq += xv * wq[t * ND + k];
    ak += xv * wk[t * ND + k];
    av += xv * wv[t * ND + k];
  }
  nq[row * ND + t] = aq;
  nk[row * ND + t] = ak;
  nv[row * ND + t] = av;
}

// ---------------- K2: attention via MFMA edge projections ----------------
// Per block (b,i), wave = head h:
//  pass1: per 128-j tile (staged hi/lo bf16, XOR-swizzled):
//         Eq/Ek [16j x 16d] fragments via mfma_16x16x32_bf16 (hi/lo split),
//         score = sum_d (nq+Eq)(nk+Ek) via 4x shfl_xor over d-lanes.
//  softmax: wave h reduces its own row via shuffles.
//  pass2: psum[h][k] = sum_j p a[j][k], adj re-read from global (L2-hot).
//  epilogue (linearity): att = sum_j p nv_j + Ve psum (f32), 4-way j-split.
#define ATJ 128
struct AttnS {
  u16 Ahi[ATJ][NE];     // 16KB, row stride 128B, byte ^= (row&7)<<4
  u16 Alo[ATJ][NE];     // 16KB
  float sc[NHD][NN];    // 12KB scores -> probs
  float psum[NHD][NE];  // 2KB
  float part[4][ND];    // 2KB epilogue partials
};

__global__ void __launch_bounds__(512) k_attn(
    const float* __restrict__ adj,
    const float* __restrict__ weq,
    const float* __restrict__ wek,
    const float* __restrict__ wev,
    const float* __restrict__ nq,
    const float* __restrict__ nk,
    const float* __restrict__ nv,
    float* __restrict__ att) {
  __shared__ AttnS s;
  int bi = blockIdx.x;     // b*N + i
  int b = bi / NN;
  int t = threadIdx.x;     // 512
  int h = t >> 6;          // wave = head
  int l = t & 63;
  int lr = l & 15, lk = l >> 4;

  // per-wave B-frags: Wq_h / Wk_h bf16 [64k x 16d], 2 K-steps each
  s16x8 BQ[2], BK[2];
  {
    const float* wqp = weq + (size_t)(h * 16 + lr) * NE + lk * 8;
    const float* wkp = wek + (size_t)(h * 16 + lr) * NE + lk * 8;
    BQ[0] = cvt_frag(wqp); BQ[1] = cvt_frag(wqp + 32);
    BK[0] = cvt_frag(wkp); BK[1] = cvt_frag(wkp + 32);
  }
  float nqd = nq[(size_t)bi * ND + h * 16 + lr];

  // ---------------- pass 1: scores ----------------
  for (int tile = 0; tile < NN / ATJ; ++tile) {
    int jbase = tile * ATJ;
    __syncthreads();  // protect tile from previous iteration's readers
    for (int p = t; p < ATJ * 8; p += 512) {
      int row = p >> 3, u = p & 7;
      const float* src = adj + ((size_t)bi * NN + jbase + row) * NE + u * 8;
      uint4 hi, lo;
      cvt8_hl(src, hi, lo);
      int byt = (row * 128 + u * 16) ^ ((row & 7) << 4);
      *(uint4*)((char*)s.Ahi + byt) = hi;
      *(uint4*)((char*)s.Alo + byt) = lo;
    }
    __syncthreads();

#pragma unroll
    for (int sub = 0; sub < ATJ / 16; ++sub) {
      int trow = sub * 16 + lr;
      int swz = (trow & 7) << 4;
      f32x4 eq = {0.f, 0.f, 0.f, 0.f}, ek = {0.f, 0.f, 0.f, 0.f};
#pragma unroll
      for (int ks = 0; ks < 2; ++ks) {
        int byt = (trow * 128 + ks * 64 + lk * 16) ^ swz;
        s16x8 ah = *(const s16x8*)((const char*)s.Ahi + byt);
        s16x8 al = *(const s16x8*)((const char*)s.Alo + byt);
        eq = MFMA16(ah, BQ[ks], eq);
        eq = MFMA16(al, BQ[ks], eq);
        ek = MFMA16(ah, BK[ks], ek);
        ek = MFMA16(al, BK[ks], ek);
      }
      // C layout: col d = lane&15, row j = (lane>>4)*4 + r
#pragma unroll
      for (int r = 0; r < 4; ++r) {
        int j = jbase + sub * 16 + lk * 4 + r;
        float kv = nk[((size_t)b * NN + j) * ND + h * 16 + lr] + ek[r];
        float prod = (nqd + eq[r]) * kv;
#pragma unroll
        for (int o = 8; o > 0; o >>= 1) prod += __shfl_xor(prod, o, 64);
        if (lr == 0) s.sc[h][j] = prod * ATT_SCALE;
      }
    }
  }
  __syncthreads();

  // ---------------- softmax: wave h owns row h ----------------
  {
    float vals[NN / 64];
    float m = -1e30f;
#pragma unroll
    for (int r = 0; r < NN / 64; ++r) {
      vals[r] = s.sc[h][l + 64 * r];
      m = fmaxf(m, vals[r]);
    }
    m = wmax64(m);
    float sum = 0.f;
#pragma unroll
    for (int r = 0; r < NN / 64; ++r) {
      vals[r] = __expf(vals[r] - m);
      sum += vals[r];
    }
    sum = wsum64(sum);
    float rinv = 1.f / sum;
#pragma unroll
    for (int r = 0; r < NN / 64; ++r) s.sc[h][l + 64 * r] = vals[r] * rinv;
  }

  // ---------------- pass 2: psum[h][k=l] = sum_j p * adj[j][k] -------------
  // adj re-read from global: coalesced 256B/wave per j, L2-hot (HBM ~2%).
  {
    float pacc = 0.f;
    const float* ab = adj + (size_t)bi * NN * NE + l;
    const float* prow = s.sc[h];
#pragma unroll 4
    for (int j = 0; j < NN; ++j) pacc += prow[j] * ab[(size_t)j * NE];
    s.psum[h][l] = pacc;
  }
  __syncthreads();

  // ---------------- epilogue: att = sum_j p nv_j + Ve psum ----------------
  {
    int c = t & 127, grp = t >> 7;  // 4-way j-split
    int hc = c >> 4;
    float acc = 0.f;
    const float* nvb = nv + (size_t)b * NN * ND + c;
    const float* pr = s.sc[hc];
#pragma unroll 4
    for (int j = grp * (NN / 4); j < (grp + 1) * (NN / 4); ++j)
      acc += pr[j] * nvb[(size_t)j * ND];
    s.part[grp][c] = acc;
  }
  __syncthreads();
  if (t < ND) {
    int c = t, hc = c >> 4;
    float acc = s.part[0][c] + s.part[1][c] + s.part[2][c] + s.part[3][c];
    const float4* wr = (const float4*)(wev + c * NE);
    const float* ps = s.psum[hc];
#pragma unroll
    for (int k4 = 0; k4 < NE / 4; ++k4) {
      float4 w4 = wr[k4];
      acc += w4.x * ps[4 * k4] + w4.y * ps[4 * k4 + 1] +
             w4.z * ps[4 * k4 + 2] + w4.w * ps[4 * k4 + 3];
    }
    // channel c -> (h=c/16, d=c%16); output position d*HEADS + h
    att[(size_t)bi * ND + (c & 15) * NHD + hc] = acc;
  }
}

// ---------------- K3: nfc1 + LN1 + FFN + LN2, serial LN reductions ---------
struct FfnS {
  float atts[ND];
  float tvb[ND];
  float x1[ND];
  float hb[NHID];
  float stats[2];  // mean, rstd
};

__global__ void k_node_ffn(const float* __restrict__ x,
                           const float* __restrict__ att,
                           const float* __restrict__ w1, const float* __restrict__ b1,
                           const float* __restrict__ g1, const float* __restrict__ bb1,
                           const float* __restrict__ w2, const float* __restrict__ b2,
                           const float* __restrict__ w3, const float* __restrict__ b3,
                           const float* __restrict__ g2, const float* __restrict__ bb2,
                           float* __restrict__ xout) {
  __shared__ FfnS s;
  int row = blockIdx.x;
  int tid = threadIdx.x;  // 256
  if (tid < ND) s.atts[tid] = att[row * ND + tid];
  __syncthreads();

  if (tid < ND) {
    float acc = b1[tid];
    for (int k = 0; k < ND; ++k) acc += s.atts[k] * w1[tid * ND + k];
    s.tvb[tid] = x[row * ND + tid] + acc;
  }
  __syncthreads();
  if (tid == 0) {
    float m = 0.f;
    for (int k = 0; k < ND; ++k) m += s.tvb[k];
    m *= (1.f / ND);
    float v = 0.f;
    for (int k = 0; k < ND; ++k) { float d = s.tvb[k] - m; v += d * d; }
    s.stats[0] = m;
    s.stats[1] = rsqrtf(v * (1.f / ND) + LN_EPS);
  }
  __syncthreads();
  if (tid < ND)
    s.x1[tid] = (s.tvb[tid] - s.stats[0]) * s.stats[1] * g1[tid] + bb1[tid];
  __syncthreads();

  {
    float acc = b2[tid];
    for (int k = 0; k < ND; ++k) acc += s.x1[k] * w2[tid * ND + k];
    s.hb[tid] = fmaxf(acc, 0.f);
  }
  __syncthreads();

  if (tid < ND) {
    float acc = b3[tid];
    for (int k = 0; k < NHID; ++k) acc += s.hb[k] * w3[tid * NHID + k];
    s.tvb[tid] = s.x1[tid] + acc;
  }
  __syncthreads();
  if (tid == 0) {
    float m = 0.f;
    for (int k = 0; k < ND; ++k) m += s.tvb[k];
    m *= (1.f / ND);
    float v = 0.f;
    for (int k = 0; k < ND; ++k) { float d = s.tvb[k] - m; v += d * d; }
    s.stats[0] = m;
    s.stats[1] = rsqrtf(v * (1.f / ND) + LN_EPS);
  }
  __syncthreads();
  if (tid < ND) {
    float o = (s.tvb[tid] - s.stats[0]) * s.stats[1] * g2[tid] + bb2[tid];
    xout[row * ND + tid] = o;  // FLOAT32 output
  }
}

// ---------------- K4: edge stage 1 via MFMA, hi/lo bf16 split --------------
#define EMT 32

struct E1M {
  u16 Ahi[EMT][EH1];   // 24KB swizzled, row stride 768B
  u16 Alo[EMT][EH1];   // 24KB
  u16 Hhi[EMT][NE];    // 4KB swizzled, row stride 128B
  u16 Hlo[EMT][NE];    // 4KB ; Hhi+Hlo reused as f32 tvb[32][64] for LN
};

__global__ void __launch_bounds__(512) k_edge1(
    const float* __restrict__ adj, const float* __restrict__ xq,
    const float* __restrict__ w1, const float* __restrict__ b1,
    const float* __restrict__ w2, const float* __restrict__ b2,
    const float* __restrict__ g, const float* __restrict__ bb,
    float* __restrict__ adj1out) {
  __shared__ E1M s;
  int bi = blockIdx.x;
  int b = bi / NN, i = bi % NN;
  int t = threadIdx.x;      // 512
  int w = t >> 6, l = t & 63;
  int m16 = (w & 1) * 16;   // wave's M sub-tile base
  int n16 = (w >> 1) * 16;  // wave's N sub-tile base
  int lr = l & 15, lk = l >> 4;

  // per-wave weight fragments in registers (f32 -> bf16 once per block)
  s16x8 B1[12], B2[2];
  {
    const float* wr = w1 + (size_t)(n16 + lr) * EH1 + lk * 8;
#pragma unroll
    for (int ks = 0; ks < 12; ++ks) B1[ks] = cvt_frag(wr + ks * 32);
    const float* w2r = w2 + (size_t)(n16 + lr) * NE + lk * 8;
#pragma unroll
    for (int ks = 0; ks < 2; ++ks) B2[ks] = cvt_frag(w2r + ks * 32);
  }
  float bias1 = b1[n16 + lr];
  float bias2 = b2[n16 + lr];
  float gl = g[l], bl = bb[l];

  for (int mt = 0; mt < NN / EMT; ++mt) {
    int jbase = mt * EMT;
    __syncthreads();
    // stage ua tile: 32 rows x 48 x 16B units (hi/lo)
    for (int p = t; p < EMT * 48; p += 512) {
      int row = p / 48, u = p % 48;
      const float* src;
      if (u < 8)
        src = adj + ((size_t)bi * NN + jbase + row) * NE + u * 8;
      else if (u < 16)
        src = adj + ((size_t)(b * NN + jbase + row) * NN + i) * NE + (u - 8) * 8;
      else if (u < 32)
        src = xq + (size_t)(b * NN + jbase + row) * ND + (u - 16) * 8;
      else
        src = xq + (size_t)bi * ND + (u - 32) * 8;
      uint4 hi, lo;
      cvt8_hl(src, hi, lo);
      int byt = (row * 768 + u * 16) ^ ((row & 7) << 4);
      *(uint4*)((char*)s.Ahi + byt) = hi;
      *(uint4*)((char*)s.Alo + byt) = lo;
    }
    __syncthreads();

    // layer1
    f32x4 acc = {0.f, 0.f, 0.f, 0.f};
    int arow = m16 + lr;
    int aswz = (arow & 7) << 4;
#pragma unroll
    for (int ks = 0; ks < 12; ++ks) {
      int byt = (arow * 768 + ks * 64 + lk * 16) ^ aswz;
      s16x8 ah = *(const s16x8*)((const char*)s.Ahi + byt);
      s16x8 al = *(const s16x8*)((const char*)s.Alo + byt);
      acc = MFMA16(ah, B1[ks], acc);
      acc = MFMA16(al, B1[ks], acc);
    }
#pragma unroll
    for (int r = 0; r < 4; ++r) {
      float hv = fmaxf(acc[r] + bias1, 0.f);
      u16 hh = bfr(hv);
      u16 hl = bfr(hv - bfu(hh));
      int row = m16 + lk * 4 + r;
      int byt = (row * 128 + (n16 + lr) * 2) ^ ((row & 7) << 4);
      *(u16*)((char*)s.Hhi + byt) = hh;
      *(u16*)((char*)s.Hlo + byt) = hl;
    }
    __syncthreads();

    // layer2
    f32x4 acc2 = {0.f, 0.f, 0.f, 0.f};
#pragma unroll
    for (int ks = 0; ks < 2; ++ks) {
      int byt = (arow * 128 + ks * 64 + lk * 16) ^ aswz;
      s16x8 ah = *(const s16x8*)((const char*)s.Hhi + byt);
      s16x8 al = *(const s16x8*)((const char*)s.Hlo + byt);
      acc2 = MFMA16(ah, B2[ks], acc2);
      acc2 = MFMA16(al, B2[ks], acc2);
    }
    __syncthreads();  // H reads done -> reuse as f32 tv buffer
    float* tvb = (float*)s.Hhi;
#pragma unroll
    for (int r = 0; r < 4; ++r) {
      int row = m16 + lk * 4 + r;
      int col = n16 + lr;
      int abyt = (row * 768 + col * 2) ^ ((row & 7) << 4);
      float aorig = bfu(*(const u16*)((const char*)s.Ahi + abyt)) +
                    bfu(*(const u16*)((const char*)s.Alo + abyt));
      tvb[row * NE + col] = aorig + acc2[r] + bias2;
    }
    __syncthreads();
    // LN: wave w handles rows w*4..w*4+3, lane = col
#pragma unroll
    for (int rr = 0; rr < EMT / 8; ++rr) {
      int row = w * (EMT / 8) + rr;
      float tv = tvb[row * NE + l];
      float mean = wsum64(tv) * (1.f / NE);
      float dv = tv - mean;
      float var = wsum64(dv * dv) * (1.f / NE);
      float o = dv * rsqrtf(var + LN_EPS) * gl + bl;
      adj1out[((size_t)bi * NN + jbase + row) * NE + l] = o;
    }
  }
}

// ---------------- K5: edge stage 2 via MFMA (in-place on d_out adj) --------
struct E2M {
  u16 Ahi[EMT][NE];    // 4KB swizzled, row stride 128B
  u16 Alo[EMT][NE];    // 4KB
  u16 Hhi[EMT][EH2];   // 8KB swizzled, row stride 256B ; reused as f32 tvb
  u16 Hlo[EMT][EH2];   // 8KB
};

__global__ void __launch_bounds__(512) k_edge2(
    float* __restrict__ adjio,
    const float* __restrict__ w3, const float* __restrict__ b3,
    const float* __restrict__ w4, const float* __restrict__ b4,
    const float* __restrict__ g, const float* __restrict__ bb) {
  __shared__ E2M s;
  int bi = blockIdx.x;
  int t = threadIdx.x;      // 512
  int w = t >> 6, l = t & 63;
  int m16 = (w & 1) * 16;
  int nb = (w >> 1) * 2;    // layer3 n16 pair base (0,2,4,6)
  int n16 = (w >> 1) * 16;  // layer4 col base
  int lr = l & 15, lk = l >> 4;

  s16x8 B3[2][2], B4[4];
  {
#pragma unroll
    for (int n = 0; n < 2; ++n) {
      const float* wr = w3 + (size_t)((nb + n) * 16 + lr) * NE + lk * 8;
#pragma unroll
      for (int ks = 0; ks < 2; ++ks) B3[n][ks] = cvt_frag(wr + ks * 32);
    }
    const float* w4r = w4 + (size_t)(n16 + lr) * EH2 + lk * 8;
#pragma unroll
    for (int ks = 0; ks < 4; ++ks) B4[ks] = cvt_frag(w4r + ks * 32);
  }
  float bias3[2] = {b3[nb * 16 + lr], b3[(nb + 1) * 16 + lr]};
  float bias4 = b4[n16 + lr];
  float gl = g[l], bl = bb[l];

  for (int mt = 0; mt < NN / EMT; ++mt) {
    int jbase = mt * EMT;
    __syncthreads();
    for (int p = t; p < EMT * 8; p += 512) {  // 256 units, threads<256 active
      int row = p >> 3, u = p & 7;
      const float* src = adjio + ((size_t)bi * NN + jbase + row) * NE + u * 8;
      uint4 hi, lo;
      cvt8_hl(src, hi, lo);
      int byt = (row * 128 + u * 16) ^ ((row & 7) << 4);
      *(uint4*)((char*)s.Ahi + byt) = hi;
      *(uint4*)((char*)s.Alo + byt) = lo;
    }
    __syncthreads();

    // layer3: out [32 x 128]
    f32x4 a3[2] = {{0.f, 0.f, 0.f, 0.f}, {0.f, 0.f, 0.f, 0.f}};
    int arow = m16 + lr;
    int aswz = (arow & 7) << 4;
#pragma unroll
    for (int ks = 0; ks < 2; ++ks) {
      int byt = (arow * 128 + ks * 64 + lk * 16) ^ aswz;
      s16x8 ah = *(const s16x8*)((const char*)s.Ahi + byt);
      s16x8 al = *(const s16x8*)((const char*)s.Alo + byt);
#pragma unroll
      for (int n = 0; n < 2; ++n) {
        a3[n] = MFMA16(ah, B3[n][ks], a3[n]);
        a3[n] = MFMA16(al, B3[n][ks], a3[n]);
      }
    }
#pragma unroll
    for (int n = 0; n < 2; ++n) {
#pragma unroll
      for (int r = 0; r < 4; ++r) {
        float hv = fmaxf(a3[n][r] + bias3[n], 0.f);
        u16 hh = bfr(hv);
        u16 hl = bfr(hv - bfu(hh));
        int row = m16 + lk * 4 + r;
        int byt = (row * 256 + ((nb + n) * 16 + lr) * 2) ^ ((row & 7) << 4);
        *(u16*)((char*)s.Hhi + byt) = hh;
        *(u16*)((char*)s.Hlo + byt) = hl;
      }
    }
    __syncthreads();

    // layer4: out [32 x 64]
    f32x4 a4 = {0.f, 0.f, 0.f, 0.f};
#pragma unroll
    for (int ks = 0; ks < 4; ++ks) {
      int byt = (arow * 256 + ks * 64 + lk * 16) ^ aswz;
      s16x8 ah = *(const s16x8*)((const char*)s.Hhi + byt);
      s16x8 al = *(const s16x8*)((const char*)s.Hlo + byt);
      a4 = MFMA16(ah, B4[ks], a4);
      a4 = MFMA16(al, B4[ks], a4);
    }
    __syncthreads();  // H reads done -> reuse as f32 tv buffer
    float* tvb = (float*)s.Hhi;
#pragma unroll
    for (int r = 0; r < 4; ++r) {
      int row = m16 + lk * 4 + r;
      int col = n16 + lr;
      int abyt = (row * 128 + col * 2) ^ ((row & 7) << 4);
      float aorig = bfu(*(const u16*)((const char*)s.Ahi + abyt)) +
                    bfu(*(const u16*)((const char*)s.Alo + abyt));
      tvb[row * NE + col] = aorig + a4[r] + bias4;
    }
    __syncthreads();
#pragma unroll
    for (int rr = 0; rr < EMT / 8; ++rr) {
      int row = w * (EMT / 8) + rr;
      float tv = tvb[row * NE + l];
      float mean = wsum64(tv) * (1.f / NE);
      float dv = tv - mean;
      float var = wsum64(dv * dv) * (1.f / NE);
      float o = dv * rsqrtf(var + LN_EPS) * gl + bl;
      adjio[((size_t)bi * NN + jbase + row) * NE + l] = o;
    }
  }
}

extern "C" void kernel_launch(void* const* d_in, const int* in_sizes, int n_in,
                              void* d_out, int out_size, void* d_ws, size_t ws_size,
                              hipStream_t stream) {
  (void)in_sizes; (void)n_in; (void)out_size; (void)d_ws; (void)ws_size;
  const float* x      = (const float*)d_in[0];
  const float* adj    = (const float*)d_in[1];
  const float* wnq    = (const float*)d_in[2];
  const float* wnk    = (const float*)d_in[3];
  const float* wnv    = (const float*)d_in[4];
  const float* weq    = (const float*)d_in[5];
  const float* wek    = (const float*)d_in[6];
  const float* wev    = (const float*)d_in[7];
  const float* nfc1_w = (const float*)d_in[8];
  const float* nfc1_b = (const float*)d_in[9];
  const float* ln1_g  = (const float*)d_in[10];
  const float* ln1_b  = (const float*)d_in[11];
  const float* nfc2_w = (const float*)d_in[12];
  const float* nfc2_b = (const float*)d_in[13];
  const float* nfc3_w = (const float*)d_in[14];
  const float* nfc3_b = (const float*)d_in[15];
  const float* ln2_g  = (const float*)d_in[16];
  const float* ln2_b  = (const float*)d_in[17];
  const float* efc1_w = (const float*)d_in[18];
  const float* efc1_b = (const float*)d_in[19];
  const float* efc2_w = (const float*)d_in[20];
  const float* efc2_b = (const float*)d_in[21];
  const float* eln1_g = (const float*)d_in[22];
  const float* eln1_b = (const float*)d_in[23];
  const float* efc3_w = (const float*)d_in[24];
  const float* efc3_b = (const float*)d_in[25];
  const float* efc4_w = (const float*)d_in[26];
  const float* efc4_b = (const float*)d_in[27];
  const float* eln2_g = (const float*)d_in[28];
  const float* eln2_b = (const float*)d_in[29];

  float* outf = (float*)d_out;          // FLOAT32 output buffer: [x ; adj]
  float* outadj = outf + XOUT_ELEMS;

  float* scratch = outf + OUT_ELEMS - SCRATCH_F32;
  float* nq  = scratch;
  float* nk  = scratch + XOUT_ELEMS;
  float* nv  = scratch + 2 * XOUT_ELEMS;
  float* att = scratch + 3 * XOUT_ELEMS;

  k_node_qkv<<<NB * NN, 128, 0, stream>>>(x, wnq, wnk, wnv, nq, nk, nv);
  k_attn<<<NB * NN, 512, 0, stream>>>(adj, weq, wek, wev, nq, nk, nv, att);
  k_node_ffn<<<NB * NN, 256, 0, stream>>>(x, att, nfc1_w, nfc1_b, ln1_g, ln1_b,
                                          nfc2_w, nfc2_b, nfc3_w, nfc3_b,
                                          ln2_g, ln2_b, outf);
  k_edge1<<<NB * NN, 512, 0, stream>>>(adj, outf, efc1_w, efc1_b, efc2_w, efc2_b,
                                       eln1_g, eln1_b, outadj);
  k_edge2<<<NB * NN, 512, 0, stream>>>(outadj, efc3_w, efc3_b, efc4_w, efc4_b,
                                       eln2_g, eln2_b);
}